// Round 3
// baseline (201.965 us; speedup 1.0000x reference)
//
#include <hip/hip_runtime.h>

#define H 4
#define Nq 4096
#define LOG2E 1.44269504088896340736f

typedef unsigned short ushortT;
typedef __attribute__((ext_vector_type(4))) short short4T;
typedef __attribute__((ext_vector_type(8))) short short8;
typedef __attribute__((ext_vector_type(4))) float floatx4;

// round-half-up f32 -> bf16 (inputs finite)
static __device__ __forceinline__ ushortT f2bf(float x) {
    unsigned int u = __builtin_bit_cast(unsigned int, x);
    return (ushortT)((u + 0x8000u) >> 16);
}

// async global->LDS, 16B per lane; LDS dest = wave-uniform base + lane*16.
// CK-style addrspace casts (generic LDS ptr: low 32 bits = LDS offset).
static __device__ __forceinline__ void gld16(const void* g, void* l) {
    __builtin_amdgcn_global_load_lds(
        reinterpret_cast<const __attribute__((address_space(1))) unsigned int*>(
            reinterpret_cast<unsigned long long>(g)),
        reinterpret_cast<__attribute__((address_space(3))) unsigned int*>(
            static_cast<unsigned int>(reinterpret_cast<unsigned long long>(l))),
        16, 0, 0);
}

// ---------------------------------------------------------------------------
// Kernel 1: QKV projection + stack + vec-activation (unchanged from R2).
// ---------------------------------------------------------------------------
__global__ __launch_bounds__(256) void qkv_kernel(
    const float* __restrict__ ax, const float* __restrict__ vx,
    const float* __restrict__ Waq, const float* __restrict__ Wvq,
    const float* __restrict__ Wak, const float* __restrict__ Wvk,
    const float* __restrict__ Wav, const float* __restrict__ Wvv,
    ushortT* __restrict__ Qg, ushortT* __restrict__ Kg, ushortT* __restrict__ Vtg)
{
    const int h     = blockIdx.y;
    const int mat   = blockIdx.z >> 1;
    const int chalf = blockIdx.z & 1;
    const int c0    = chalf * 8;
    const int n     = blockIdx.x * 256 + threadIdx.x;

    const float* Wa = (mat == 0 ? Waq : (mat == 1 ? Wak : Wav)) + h * (16 * 64);
    const float* Wv = (mat == 0 ? Wvq : (mat == 1 ? Wvk : Wvv)) + h * (16 * 16);

    float axr[64];
    {
        const floatx4* p = (const floatx4*)(ax + (size_t)n * 64);
        #pragma unroll
        for (int i = 0; i < 16; i++) {
            floatx4 t = p[i];
            axr[4*i+0] = t.x; axr[4*i+1] = t.y; axr[4*i+2] = t.z; axr[4*i+3] = t.w;
        }
    }
    float vxr[48];
    {
        const floatx4* p = (const floatx4*)(vx + (size_t)n * 48);
        #pragma unroll
        for (int i = 0; i < 12; i++) {
            floatx4 t = p[i];
            vxr[4*i+0] = t.x; vxr[4*i+1] = t.y; vxr[4*i+2] = t.z; vxr[4*i+3] = t.w;
        }
    }

    float acca[8] = {};
    float accv[8][3] = {};
    #pragma unroll
    for (int d = 0; d < 64; d++) {
        #pragma unroll
        for (int cc = 0; cc < 8; cc++)
            acca[cc] = fmaf(Wa[(c0 + cc) * 64 + d], axr[d], acca[cc]);
    }
    #pragma unroll
    for (int j = 0; j < 16; j++) {
        #pragma unroll
        for (int cc = 0; cc < 8; cc++) {
            const float w = Wv[(c0 + cc) * 16 + j];
            accv[cc][0] = fmaf(w, vxr[3*j+0], accv[cc][0]);
            accv[cc][1] = fmaf(w, vxr[3*j+1], accv[cc][1]);
            accv[cc][2] = fmaf(w, vxr[3*j+2], accv[cc][2]);
        }
    }

    const float sc_extra = (mat == 0) ? LOG2E : 1.0f;
    __attribute__((aligned(16))) ushortT ob[32];
    #pragma unroll
    for (int cc = 0; cc < 8; cc++) {
        float a = acca[cc], v0 = accv[cc][0], v1 = accv[cc][1], v2 = accv[cc][2];
        float s = 1.0f;
        if (mat < 2) {
            const float nsq = a*a + v0*v0 + v1*v1 + v2*v2;
            s = rsqrtf(sqrtf(1.0f + nsq)) * sc_extra;   // (1+nsq)^(-1/4)
        }
        ob[4*cc+0] = f2bf(a  * s);
        ob[4*cc+1] = f2bf(v0 * s);
        ob[4*cc+2] = f2bf(v1 * s);
        ob[4*cc+3] = f2bf(v2 * s);
    }

    if (mat < 2) {
        ushortT* dst = (mat == 0 ? Qg : Kg) + ((size_t)(h * Nq + n)) * 64 + c0 * 4;
        #pragma unroll
        for (int i = 0; i < 4; i++) ((short8*)dst)[i] = ((const short8*)ob)[i];
    } else {
        #pragma unroll
        for (int cc = 0; cc < 8; cc++)
            #pragma unroll
            for (int j = 0; j < 4; j++) {
                const int d = c0 * 4 + cc * 4 + j;
                Vtg[((size_t)(h * 64 + d)) * Nq + n] = ob[4*cc+j];  // coalesced
            }
    }
}

// ---------------------------------------------------------------------------
// Kernel 2 (v3): transposed-S flash attention.
//   Block = 2 waves x 32 q (qtile 64). QK computed as mfma(K, Q) -> S^T in
//   regs (row=key=quad*4+r, col=q=ln): P stays in REGISTERS (no LDS round
//   trip); PV uses K=32 MFMA with V fetched as two b64s per 32-key chunk.
//   K/V tiles staged via global_load_lds (16B) into XOR-swizzled linear LDS
//   (part ^= row&7): kf reads are 8-phase ideal, vf 4-phase ideal.
// ---------------------------------------------------------------------------
__global__ __launch_bounds__(128, 4) void attn_kernel(
    const ushortT* __restrict__ Qg, const ushortT* __restrict__ Kg,
    const ushortT* __restrict__ Vtg,
    const float* __restrict__ pos_q, const float* __restrict__ pos_k,
    float* __restrict__ partO, float* __restrict__ partL,
    int segs, int nkt)
{
    __shared__ __attribute__((aligned(16))) ushortT kE[64 * 64];  // swizzled [key][feat]
    __shared__ __attribute__((aligned(16))) ushortT vE[64 * 64];  // swizzled [feat][key]
    __shared__ floatx4 poskE[64];   // (kx, ky, kz, -c|pk|^2)
    __shared__ floatx4 pqE[64];     // (2c*qx, 2c*qy, 2c*qz, -c|pq|^2)

    const int tid  = threadIdx.x;
    const int w    = tid >> 6;
    const int lane = tid & 63;
    const int quad = lane >> 4;
    const int ln   = lane & 15;
    const int m7   = ln & 7;
    const int h    = blockIdx.y;
    const int seg  = blockIdx.z;
    const int qb   = blockIdx.x * 64;
    const int qw   = qb + w * 32;

    const float c = LOG2E / (float)(1 << (2 * h));   // log2e / r0sq[h]

    // stage per-block pos_q constants
    if (tid < 64) {
        const int q = qb + tid;
        const float x = pos_q[(size_t)(h * Nq + q) * 3 + 0];
        const float y = pos_q[(size_t)(h * Nq + q) * 3 + 1];
        const float z = pos_q[(size_t)(h * Nq + q) * 3 + 2];
        pqE[tid] = (floatx4){2.f*c*x, 2.f*c*y, 2.f*c*z, -c*(x*x + y*y + z*z)};
    }

    // Q fragments (also valid as B-operand; Q pre-scaled by log2e)
    short8 qf[2][2];
    #pragma unroll
    for (int qg = 0; qg < 2; qg++) {
        const short8* qp = (const short8*)(Qg + ((size_t)(h*Nq + qw + qg*16 + ln))*64 + quad*8);
        qf[qg][0] = qp[0];
        qf[qg][1] = qp[4];
    }
    __syncthreads();
    const floatx4 pql[2] = { pqE[w*32 + ln], pqE[w*32 + 16 + ln] };

    floatx4 O[2][4] = {};            // [qg][featgroup]: q=quad*4+r, feat=g*16+ln
    float lacc[2] = {0.f, 0.f};

    const int k0seg = seg * nkt * 64;
    for (int kt = 0; kt < nkt; kt++) {
        const int k0 = k0seg + kt * 64;
        __syncthreads();             // prev-tile reads done before DMA writes
        // --- async-stage K and Vt (512 x 16B chunks each), XOR-swizzled ---
        #pragma unroll
        for (int i = 0; i < 4; i++) {
            const int cbase = i * 128 + w * 64;   // wave-uniform
            const int cc    = cbase + lane;
            const int row   = cc >> 3;
            const int part  = (cc & 7) ^ (row & 7);
            gld16(Kg + ((size_t)(h*Nq + k0 + row))*64 + part*8, (char*)kE + cbase*16);
            gld16(Vtg + ((size_t)(h*64 + row))*Nq + k0 + part*8, (char*)vE + cbase*16);
        }
        if (tid < 64) {
            const float x = pos_k[(size_t)(h*Nq + k0 + tid)*3 + 0];
            const float y = pos_k[(size_t)(h*Nq + k0 + tid)*3 + 1];
            const float z = pos_k[(size_t)(h*Nq + k0 + tid)*3 + 2];
            poskE[tid] = (floatx4){x, y, z, -c*(x*x + y*y + z*z)};
        }
        __syncthreads();

        // --- two 32-key chunks ---
        #pragma unroll
        for (int c2 = 0; c2 < 2; c2++) {
            short4T ph[2][2];        // [kk2][qg] P bf16, keys quad*4+r
            #pragma unroll
            for (int kk2 = 0; kk2 < 2; kk2++) {
                const int kk  = c2*2 + kk2;
                const int row = kk*16 + ln;
                const int p0  = quad ^ m7;
                const short8 kf0 = *(const short8*)&kE[row*64 + p0*8];
                const short8 kf1 = *(const short8*)&kE[row*64 + (p0^4)*8];
                const floatx4 pk0 = poskE[kk*16 + quad*4 + 0];
                const floatx4 pk1 = poskE[kk*16 + quad*4 + 1];
                const floatx4 pk2 = poskE[kk*16 + quad*4 + 2];
                const floatx4 pk3 = poskE[kk*16 + quad*4 + 3];
                #pragma unroll
                for (int qg = 0; qg < 2; qg++) {
                    floatx4 S = {0.f, 0.f, 0.f, 0.f};
                    S = __builtin_amdgcn_mfma_f32_16x16x32_bf16(kf0, qf[qg][0], S, 0, 0, 0);
                    S = __builtin_amdgcn_mfma_f32_16x16x32_bf16(kf1, qf[qg][1], S, 0, 0, 0);
                    const floatx4 pq = pql[qg];
                    const float p0v = __builtin_amdgcn_exp2f(S[0] +
                        fmaf(pq.x, pk0.x, fmaf(pq.y, pk0.y, fmaf(pq.z, pk0.z, pq.w + pk0.w))));
                    const float p1v = __builtin_amdgcn_exp2f(S[1] +
                        fmaf(pq.x, pk1.x, fmaf(pq.y, pk1.y, fmaf(pq.z, pk1.z, pq.w + pk1.w))));
                    const float p2v = __builtin_amdgcn_exp2f(S[2] +
                        fmaf(pq.x, pk2.x, fmaf(pq.y, pk2.y, fmaf(pq.z, pk2.z, pq.w + pk2.w))));
                    const float p3v = __builtin_amdgcn_exp2f(S[3] +
                        fmaf(pq.x, pk3.x, fmaf(pq.y, pk3.y, fmaf(pq.z, pk3.z, pq.w + pk3.w))));
                    lacc[qg] += (p0v + p1v) + (p2v + p3v);
                    ph[kk2][qg] = (short4T){ (short)f2bf(p0v), (short)f2bf(p1v),
                                             (short)f2bf(p2v), (short)f2bf(p3v) };
                }
            }
            // P A-frags for K=32 (positions quad*8+j <-> keys c2*32 + [quad*4+j | 16+quad*4+(j-4)])
            short8 pf[2];
            #pragma unroll
            for (int qg = 0; qg < 2; qg++)
                pf[qg] = (short8){ ph[0][qg].x, ph[0][qg].y, ph[0][qg].z, ph[0][qg].w,
                                   ph[1][qg].x, ph[1][qg].y, ph[1][qg].z, ph[1][qg].w };
            #pragma unroll
            for (int g = 0; g < 4; g++) {
                const int feat = g*16 + ln;
                const int ci   = c2*4 + (quad >> 1);       // 16B chunk idx (lo keys)
                const int pt   = ci ^ m7;
                const int ho   = (quad & 1) * 4;           // 8B half, in shorts
                const short4T vlo = *(const short4T*)&vE[feat*64 + pt*8 + ho];
                const short4T vhi = *(const short4T*)&vE[feat*64 + (pt^2)*8 + ho];
                const short8 vf = (short8){ vlo.x, vlo.y, vlo.z, vlo.w,
                                            vhi.x, vhi.y, vhi.z, vhi.w };
                O[0][g] = __builtin_amdgcn_mfma_f32_16x16x32_bf16(pf[0], vf, O[0][g], 0, 0, 0);
                O[1][g] = __builtin_amdgcn_mfma_f32_16x16x32_bf16(pf[1], vf, O[1][g], 0, 0, 0);
            }
        }
    }

    // l: sum across quads (q = ln per lane)
    #pragma unroll
    for (int qg = 0; qg < 2; qg++) {
        float v = lacc[qg];
        v += __shfl_xor(v, 16, 64);
        v += __shfl_xor(v, 32, 64);
        lacc[qg] = v;
    }

    const int hs = h * segs + seg;
    #pragma unroll
    for (int qg = 0; qg < 2; qg++)
        #pragma unroll
        for (int r = 0; r < 4; r++) {
            const int q = qw + qg*16 + quad*4 + r;
            const size_t base = ((size_t)hs * Nq + q) * 64;
            #pragma unroll
            for (int g = 0; g < 4; g++)
                partO[base + g*16 + ln] = O[qg][g][r];
        }
    if (lane < 16) {
        #pragma unroll
        for (int qg = 0; qg < 2; qg++)
            partL[(size_t)hs * Nq + qw + qg*16 + ln] = lacc[qg];
    }
}

// ---------------------------------------------------------------------------
// Kernel 3: merge split-K partials, divide by (l*sqrt(N)), transpose to
//   Of[h][d][n].
// ---------------------------------------------------------------------------
__global__ __launch_bounds__(256) void reduce_kernel(
    const float* __restrict__ partO, const float* __restrict__ partL,
    float* __restrict__ Of, int segs)
{
    __shared__ float T[64 * 65];
    __shared__ float linv[64];
    const int tid = threadIdx.x;
    const int q0  = blockIdx.x * 64;
    const int h   = blockIdx.y;

    if (tid < 64) {
        float s = 0.f;
        for (int sg = 0; sg < segs; sg++)
            s += partL[(size_t)(h * segs + sg) * Nq + q0 + tid];
        linv[tid] = 1.0f / (s * 64.0f);          // 1/(l*sqrt(N))
    }
    __syncthreads();

    const int w = tid >> 6, lane = tid & 63;
    #pragma unroll
    for (int k = 0; k < 16; k++) {
        const int q = k * 4 + w;
        const int d = lane;
        float acc = 0.f;
        for (int sg = 0; sg < segs; sg++)
            acc += partO[((size_t)(h * segs + sg) * Nq + q0 + q) * 64 + d];
        T[d * 65 + q] = acc * linv[q];
    }
    __syncthreads();
    #pragma unroll
    for (int k = 0; k < 16; k++) {
        const int d = k * 4 + w;
        const int q = lane;
        Of[(size_t)(h * 64 + d) * Nq + q0 + q] = T[d * 65 + q];
    }
}

// ---------------------------------------------------------------------------
// Kernel 4: output projection. ay = O[0:16]; vy[i][v] = O[16+3i+v].
// ---------------------------------------------------------------------------
__global__ __launch_bounds__(256) void proj_kernel(
    const float* __restrict__ Of, const float* __restrict__ Wao,
    const float* __restrict__ Wvo, float* __restrict__ out)
{
    const int tid  = threadIdx.x;
    const int w    = tid >> 6;
    const int lane = tid & 63;
    const int n    = blockIdx.x * 64 + lane;

    float aacc[16] = {};
    float vacc[4][3] = {};

    for (int h = 0; h < 4; h++) {
        float oh[64];
        #pragma unroll
        for (int d = 0; d < 64; d++)
            oh[d] = Of[(size_t)(h * 64 + d) * Nq + n];
        #pragma unroll
        for (int jj = 0; jj < 16; jj++) {
            const int j = w * 16 + jj;
            float acc = aacc[jj];
            #pragma unroll
            for (int i = 0; i < 16; i++)
                acc = fmaf(Wao[(h * 64 + j) * 16 + i], oh[i], acc);
            aacc[jj] = acc;
        }
        #pragma unroll
        for (int jj = 0; jj < 4; jj++) {
            const int j = w * 4 + jj;
            #pragma unroll
            for (int i = 0; i < 16; i++) {
                const float wv = Wvo[(h * 16 + j) * 16 + i];
                vacc[jj][0] = fmaf(wv, oh[16 + 3 * i + 0], vacc[jj][0]);
                vacc[jj][1] = fmaf(wv, oh[16 + 3 * i + 1], vacc[jj][1]);
                vacc[jj][2] = fmaf(wv, oh[16 + 3 * i + 2], vacc[jj][2]);
            }
        }
    }
    #pragma unroll
    for (int jj = 0; jj < 16; jj++)
        out[(size_t)n * 64 + w * 16 + jj] = aacc[jj];
    float* outv = out + (size_t)Nq * 64;
    #pragma unroll
    for (int jj = 0; jj < 4; jj++)
        #pragma unroll
        for (int v = 0; v < 3; v++)
            outv[((size_t)n * 16 + w * 4 + jj) * 3 + v] = vacc[jj][v];
}

// ---------------------------------------------------------------------------
extern "C" void kernel_launch(void* const* d_in, const int* in_sizes, int n_in,
                              void* d_out, int out_size, void* d_ws, size_t ws_size,
                              hipStream_t stream)
{
    const float* ax    = (const float*)d_in[0];
    const float* vx    = (const float*)d_in[1];
    const float* pos_k = (const float*)d_in[2];
    const float* pos_q = (const float*)d_in[3];
    const float* Waq   = (const float*)d_in[4];
    const float* Wvq   = (const float*)d_in[5];
    const float* Wak   = (const float*)d_in[6];
    const float* Wvk   = (const float*)d_in[7];
    const float* Wav   = (const float*)d_in[8];
    const float* Wvv   = (const float*)d_in[9];
    const float* Wao   = (const float*)d_in[10];
    const float* Wvo   = (const float*)d_in[11];
    float* out = (float*)d_out;

    const size_t MB = 1024 * 1024;
    // SEG=8 needs ~42.8 MB; fall back to SEG=4 (~26.8 MB, known-good) if tight.
    const size_t need8 = 6*MB + (size_t)H*8*Nq*64*4 + (size_t)H*8*Nq*4 + 4*MB;
    const int segs = (ws_size >= need8) ? 8 : 4;
    const int nkt  = (Nq / segs) / 64;

    char* ws = (char*)d_ws;
    ushortT* Qg  = (ushortT*)(ws);
    ushortT* Kg  = (ushortT*)(ws + 2*MB);
    ushortT* Vtg = (ushortT*)(ws + 4*MB);
    float* partO = (float*)(ws + 6*MB);
    float* partL = (float*)(ws + 6*MB + (size_t)H*segs*Nq*64*4);
    float* Of    = (float*)((char*)partL + (size_t)H*segs*Nq*4);

    qkv_kernel<<<dim3(Nq/256, H, 6), 256, 0, stream>>>(
        ax, vx, Waq, Wvq, Wak, Wvk, Wav, Wvv, Qg, Kg, Vtg);
    attn_kernel<<<dim3(Nq/64, H, segs), 128, 0, stream>>>(
        Qg, Kg, Vtg, pos_q, pos_k, partO, partL, segs, nkt);
    reduce_kernel<<<dim3(Nq/64, H), 256, 0, stream>>>(partO, partL, Of, segs);
    proj_kernel<<<dim3(Nq/64), 256, 0, stream>>>(Of, Wao, Wvo, out);
}

// Round 4
// 162.818 us; speedup vs baseline: 1.2404x; 1.2404x over previous
//
#include <hip/hip_runtime.h>

#define H 4
#define Nq 4096
#define SEG 4
#define NKT ((Nq / SEG) / 64)
#define LOG2E 1.44269504088896340736f

typedef unsigned short ushortT;
typedef __attribute__((ext_vector_type(4))) short short4T;
typedef __attribute__((ext_vector_type(8))) short short8;
typedef __attribute__((ext_vector_type(4))) float floatx4;

// raw pipeline primitives: wait own DMA, then barrier WITHOUT the compiler's
// vmcnt(0)+lgkmcnt(0) drain (that drain is the structural stall in the
// __syncthreads version -- it would also wait the prefetch DMA).
#define WAIT_VM0() asm volatile("s_waitcnt vmcnt(0)" ::: "memory")
#define BARRIER()  asm volatile("s_barrier" ::: "memory")

// round-half-up f32 -> bf16 (inputs finite)
static __device__ __forceinline__ ushortT f2bf(float x) {
    unsigned int u = __builtin_bit_cast(unsigned int, x);
    return (ushortT)((u + 0x8000u) >> 16);
}

// async global->LDS, 16B per lane; LDS dest = wave-uniform base + lane*16.
static __device__ __forceinline__ void gld16(const void* g, void* l) {
    __builtin_amdgcn_global_load_lds(
        reinterpret_cast<const __attribute__((address_space(1))) unsigned int*>(
            reinterpret_cast<unsigned long long>(g)),
        reinterpret_cast<__attribute__((address_space(3))) unsigned int*>(
            static_cast<unsigned int>(reinterpret_cast<unsigned long long>(l))),
        16, 0, 0);
}

// ---------------------------------------------------------------------------
// Kernel 0: pos feature prep. pq4 = (2c*x, 2c*y, 2c*z, -c|p|^2),
//           pk4 = (x, y, z, -c|p|^2), c = log2e / r0sq[h].
// ---------------------------------------------------------------------------
__global__ __launch_bounds__(256) void pos_prep_kernel(
    const float* __restrict__ pos_q, const float* __restrict__ pos_k,
    floatx4* __restrict__ pq4, floatx4* __restrict__ pk4)
{
    const int n = blockIdx.x * 256 + threadIdx.x;
    const int h = blockIdx.y;
    const float c = LOG2E / (float)(1 << (2 * h));
    {
        const float* p = pos_q + ((size_t)h * Nq + n) * 3;
        const float x = p[0], y = p[1], z = p[2];
        pq4[(size_t)h * Nq + n] = (floatx4){2.f*c*x, 2.f*c*y, 2.f*c*z,
                                            -c * (x*x + y*y + z*z)};
    }
    {
        const float* p = pos_k + ((size_t)h * Nq + n) * 3;
        const float x = p[0], y = p[1], z = p[2];
        pk4[(size_t)h * Nq + n] = (floatx4){x, y, z, -c * (x*x + y*y + z*z)};
    }
}

// ---------------------------------------------------------------------------
// Kernel 1: QKV projection + stack + vec-activation (unchanged from R2/R3).
// ---------------------------------------------------------------------------
__global__ __launch_bounds__(256) void qkv_kernel(
    const float* __restrict__ ax, const float* __restrict__ vx,
    const float* __restrict__ Waq, const float* __restrict__ Wvq,
    const float* __restrict__ Wak, const float* __restrict__ Wvk,
    const float* __restrict__ Wav, const float* __restrict__ Wvv,
    ushortT* __restrict__ Qg, ushortT* __restrict__ Kg, ushortT* __restrict__ Vtg)
{
    const int h     = blockIdx.y;
    const int mat   = blockIdx.z >> 1;
    const int chalf = blockIdx.z & 1;
    const int c0    = chalf * 8;
    const int n     = blockIdx.x * 256 + threadIdx.x;

    const float* Wa = (mat == 0 ? Waq : (mat == 1 ? Wak : Wav)) + h * (16 * 64);
    const float* Wv = (mat == 0 ? Wvq : (mat == 1 ? Wvk : Wvv)) + h * (16 * 16);

    float axr[64];
    {
        const floatx4* p = (const floatx4*)(ax + (size_t)n * 64);
        #pragma unroll
        for (int i = 0; i < 16; i++) {
            floatx4 t = p[i];
            axr[4*i+0] = t.x; axr[4*i+1] = t.y; axr[4*i+2] = t.z; axr[4*i+3] = t.w;
        }
    }
    float vxr[48];
    {
        const floatx4* p = (const floatx4*)(vx + (size_t)n * 48);
        #pragma unroll
        for (int i = 0; i < 12; i++) {
            floatx4 t = p[i];
            vxr[4*i+0] = t.x; vxr[4*i+1] = t.y; vxr[4*i+2] = t.z; vxr[4*i+3] = t.w;
        }
    }

    float acca[8] = {};
    float accv[8][3] = {};
    #pragma unroll
    for (int d = 0; d < 64; d++) {
        #pragma unroll
        for (int cc = 0; cc < 8; cc++)
            acca[cc] = fmaf(Wa[(c0 + cc) * 64 + d], axr[d], acca[cc]);
    }
    #pragma unroll
    for (int j = 0; j < 16; j++) {
        #pragma unroll
        for (int cc = 0; cc < 8; cc++) {
            const float w = Wv[(c0 + cc) * 16 + j];
            accv[cc][0] = fmaf(w, vxr[3*j+0], accv[cc][0]);
            accv[cc][1] = fmaf(w, vxr[3*j+1], accv[cc][1]);
            accv[cc][2] = fmaf(w, vxr[3*j+2], accv[cc][2]);
        }
    }

    const float sc_extra = (mat == 0) ? LOG2E : 1.0f;
    __attribute__((aligned(16))) ushortT ob[32];
    #pragma unroll
    for (int cc = 0; cc < 8; cc++) {
        float a = acca[cc], v0 = accv[cc][0], v1 = accv[cc][1], v2 = accv[cc][2];
        float s = 1.0f;
        if (mat < 2) {
            const float nsq = a*a + v0*v0 + v1*v1 + v2*v2;
            s = rsqrtf(sqrtf(1.0f + nsq)) * sc_extra;   // (1+nsq)^(-1/4)
        }
        ob[4*cc+0] = f2bf(a  * s);
        ob[4*cc+1] = f2bf(v0 * s);
        ob[4*cc+2] = f2bf(v1 * s);
        ob[4*cc+3] = f2bf(v2 * s);
    }

    if (mat < 2) {
        ushortT* dst = (mat == 0 ? Qg : Kg) + ((size_t)(h * Nq + n)) * 64 + c0 * 4;
        #pragma unroll
        for (int i = 0; i < 4; i++) ((short8*)dst)[i] = ((const short8*)ob)[i];
    } else {
        #pragma unroll
        for (int cc = 0; cc < 8; cc++)
            #pragma unroll
            for (int j = 0; j < 4; j++) {
                const int d = c0 * 4 + cc * 4 + j;
                Vtg[((size_t)(h * 64 + d)) * Nq + n] = ob[4*cc+j];  // coalesced
            }
    }
}

// ---------------------------------------------------------------------------
// Kernel 2 (v4): pipelined transposed-S flash attention.
//   Structure as R3 (register P, K=32 PV, swizzled LDS, gld16 staging) but:
//   - double-buffered kE/vE/posE
//   - raw s_barrier + manual vmcnt(0): DMA(t+1) issued after barrier(t) and
//     overlaps compute(t); no compiler vmcnt-drain at the barrier.
//   - pos features precomputed (pq4/pk4), staged by the same DMA.
// ---------------------------------------------------------------------------
__global__ __launch_bounds__(128, 4) void attn_kernel(
    const ushortT* __restrict__ Qg, const ushortT* __restrict__ Kg,
    const ushortT* __restrict__ Vtg,
    const floatx4* __restrict__ pq4, const floatx4* __restrict__ pk4,
    float* __restrict__ partO, float* __restrict__ partL)
{
    __shared__ __attribute__((aligned(16))) ushortT kE[2][64 * 64];  // swizzled [key][feat]
    __shared__ __attribute__((aligned(16))) ushortT vE[2][64 * 64];  // swizzled [feat][key]
    __shared__ __attribute__((aligned(16))) floatx4 posE[2][64];     // pk features

    const int tid  = threadIdx.x;
    const int w    = tid >> 6;
    const int lane = tid & 63;
    const int quad = lane >> 4;
    const int ln   = lane & 15;
    const int m7   = ln & 7;
    const int h    = blockIdx.y;
    const int seg  = blockIdx.z;
    const int qw   = blockIdx.x * 64 + w * 32;      // wave's 32 queries

    // Q fragments (B-operand; Q pre-scaled by log2e) + pq features, direct global
    short8 qf[2][2];
    floatx4 pql[2];
    #pragma unroll
    for (int qg = 0; qg < 2; qg++) {
        const short8* qp = (const short8*)(Qg + ((size_t)(h*Nq + qw + qg*16 + ln))*64 + quad*8);
        qf[qg][0] = qp[0];
        qf[qg][1] = qp[4];
        pql[qg]   = pq4[(size_t)h*Nq + qw + qg*16 + ln];
    }

    floatx4 O[2][4] = {};            // [qg][featgroup]: q=quad*4+r, feat=g*16+ln
    float lacc[2] = {0.f, 0.f};

    const int k0seg = seg * NKT * 64;

    // --- DMA stage of one 64-key tile into buffer b (wave-cooperative) ---
    auto stage = [&](int k0, int b) {
        #pragma unroll
        for (int i = 0; i < 4; i++) {
            const int cbase = i * 128 + w * 64;     // wave-uniform LDS chunk base
            const int cc    = cbase + lane;
            const int row   = cc >> 3;
            const int part  = (cc & 7) ^ (row & 7); // XOR swizzle
            gld16(Kg + ((size_t)(h*Nq + k0 + row))*64 + part*8, (char*)kE[b] + cbase*16);
            gld16(Vtg + ((size_t)(h*64 + row))*Nq + k0 + part*8, (char*)vE[b] + cbase*16);
        }
        if (w == 0)                                  // wave-uniform branch
            gld16(pk4 + (size_t)h*Nq + k0 + lane, (char*)posE[b]);
    };

    stage(k0seg, 0);
    int buf = 0;

    #pragma unroll 1
    for (int kt = 0; kt < NKT; kt++) {
        WAIT_VM0();       // own DMA(t) complete (only tile t is outstanding here)
        BARRIER();        // other wave's DMA(t) also complete; compute(t-1) done
        if (kt + 1 < NKT) stage(k0seg + (kt + 1) * 64, buf ^ 1);  // overlaps compute(t)

        const ushortT* kb = kE[buf];
        const ushortT* vb = vE[buf];
        const floatx4* pb = posE[buf];

        #pragma unroll
        for (int c2 = 0; c2 < 2; c2++) {
            short4T ph[2][2];        // [kk2][qg] P bf16, keys quad*4+r
            #pragma unroll
            for (int kk2 = 0; kk2 < 2; kk2++) {
                const int kk  = c2*2 + kk2;
                const int row = kk*16 + ln;
                const int p0  = quad ^ m7;
                const short8 kf0 = *(const short8*)&kb[row*64 + p0*8];
                const short8 kf1 = *(const short8*)&kb[row*64 + (p0^4)*8];
                const floatx4 pk0 = pb[kk*16 + quad*4 + 0];
                const floatx4 pk1 = pb[kk*16 + quad*4 + 1];
                const floatx4 pk2 = pb[kk*16 + quad*4 + 2];
                const floatx4 pk3 = pb[kk*16 + quad*4 + 3];
                #pragma unroll
                for (int qg = 0; qg < 2; qg++) {
                    floatx4 S = {0.f, 0.f, 0.f, 0.f};
                    S = __builtin_amdgcn_mfma_f32_16x16x32_bf16(kf0, qf[qg][0], S, 0, 0, 0);
                    S = __builtin_amdgcn_mfma_f32_16x16x32_bf16(kf1, qf[qg][1], S, 0, 0, 0);
                    const floatx4 pq = pql[qg];
                    const float p0v = __builtin_amdgcn_exp2f(S[0] +
                        fmaf(pq.x, pk0.x, fmaf(pq.y, pk0.y, fmaf(pq.z, pk0.z, pq.w + pk0.w))));
                    const float p1v = __builtin_amdgcn_exp2f(S[1] +
                        fmaf(pq.x, pk1.x, fmaf(pq.y, pk1.y, fmaf(pq.z, pk1.z, pq.w + pk1.w))));
                    const float p2v = __builtin_amdgcn_exp2f(S[2] +
                        fmaf(pq.x, pk2.x, fmaf(pq.y, pk2.y, fmaf(pq.z, pk2.z, pq.w + pk2.w))));
                    const float p3v = __builtin_amdgcn_exp2f(S[3] +
                        fmaf(pq.x, pk3.x, fmaf(pq.y, pk3.y, fmaf(pq.z, pk3.z, pq.w + pk3.w))));
                    lacc[qg] += (p0v + p1v) + (p2v + p3v);
                    ph[kk2][qg] = (short4T){ (short)f2bf(p0v), (short)f2bf(p1v),
                                             (short)f2bf(p2v), (short)f2bf(p3v) };
                }
            }
            short8 pf[2];
            #pragma unroll
            for (int qg = 0; qg < 2; qg++)
                pf[qg] = (short8){ ph[0][qg].x, ph[0][qg].y, ph[0][qg].z, ph[0][qg].w,
                                   ph[1][qg].x, ph[1][qg].y, ph[1][qg].z, ph[1][qg].w };
            #pragma unroll
            for (int g = 0; g < 4; g++) {
                const int feat = g*16 + ln;
                const int ci   = c2*4 + (quad >> 1);       // 16B chunk idx (lo keys)
                const int pt   = ci ^ m7;
                const int ho   = (quad & 1) * 4;           // 8B half, in shorts
                const short4T vlo = *(const short4T*)&vb[feat*64 + pt*8 + ho];
                const short4T vhi = *(const short4T*)&vb[feat*64 + (pt^2)*8 + ho];
                const short8 vf = (short8){ vlo.x, vlo.y, vlo.z, vlo.w,
                                            vhi.x, vhi.y, vhi.z, vhi.w };
                O[0][g] = __builtin_amdgcn_mfma_f32_16x16x32_bf16(pf[0], vf, O[0][g], 0, 0, 0);
                O[1][g] = __builtin_amdgcn_mfma_f32_16x16x32_bf16(pf[1], vf, O[1][g], 0, 0, 0);
            }
        }
        buf ^= 1;
    }

    // l: sum across quads (q = ln per lane)
    #pragma unroll
    for (int qg = 0; qg < 2; qg++) {
        float v = lacc[qg];
        v += __shfl_xor(v, 16, 64);
        v += __shfl_xor(v, 32, 64);
        lacc[qg] = v;
    }

    const int hs = h * SEG + seg;
    #pragma unroll
    for (int qg = 0; qg < 2; qg++)
        #pragma unroll
        for (int r = 0; r < 4; r++) {
            const int q = qw + qg*16 + quad*4 + r;
            const size_t base = ((size_t)hs * Nq + q) * 64;
            #pragma unroll
            for (int g = 0; g < 4; g++)
                partO[base + g*16 + ln] = O[qg][g][r];
        }
    if (lane < 16) {
        #pragma unroll
        for (int qg = 0; qg < 2; qg++)
            partL[(size_t)hs * Nq + qw + qg*16 + ln] = lacc[qg];
    }
}

// ---------------------------------------------------------------------------
// Kernel 3 (fused): merge split-K partials + normalize + project.
//   Per block: 64 queries. For each h: T[d][q] = merged O; then project from
//   T directly (no Of round-trip). ay = O[0:16]; vy[i][v] = O[16+3i+v].
// ---------------------------------------------------------------------------
__global__ __launch_bounds__(256) void finish_kernel(
    const float* __restrict__ partO, const float* __restrict__ partL,
    const float* __restrict__ Wao, const float* __restrict__ Wvo,
    float* __restrict__ out)
{
    __shared__ float T[64 * 65];
    __shared__ float linvS[4][64];
    const int tid  = threadIdx.x;
    const int w    = tid >> 6;
    const int lane = tid & 63;
    const int q0   = blockIdx.x * 64;
    const int n    = q0 + lane;

    // all-head 1/(l*sqrt(N)): thread (w=h, lane=q)
    {
        float s = 0.f;
        #pragma unroll
        for (int sg = 0; sg < SEG; sg++)
            s += partL[(size_t)(w * SEG + sg) * Nq + q0 + lane];
        linvS[w][lane] = 1.0f / (s * 64.0f);
    }
    __syncthreads();

    float aacc[16] = {};
    float vacc[4][3] = {};

    for (int h = 0; h < 4; h++) {
        // merge phase: T[d*65+q]
        #pragma unroll
        for (int k = 0; k < 16; k++) {
            const int q = k * 4 + w;
            const int d = lane;
            float acc = 0.f;
            #pragma unroll
            for (int sg = 0; sg < SEG; sg++)
                acc += partO[((size_t)(h * SEG + sg) * Nq + q0 + q) * 64 + d];
            T[d * 65 + q] = acc * linvS[h][q];
        }
        __syncthreads();

        // project phase: oh[d] = T[d][lane]
        float oh[64];
        #pragma unroll
        for (int d = 0; d < 64; d++)
            oh[d] = T[d * 65 + lane];
        #pragma unroll
        for (int jj = 0; jj < 16; jj++) {
            const int j = w * 16 + jj;
            float acc = aacc[jj];
            #pragma unroll
            for (int i = 0; i < 16; i++)
                acc = fmaf(Wao[(h * 64 + j) * 16 + i], oh[i], acc);
            aacc[jj] = acc;
        }
        #pragma unroll
        for (int jj = 0; jj < 4; jj++) {
            const int j = w * 4 + jj;
            #pragma unroll
            for (int i = 0; i < 16; i++) {
                const float wv = Wvo[(h * 16 + j) * 16 + i];
                vacc[jj][0] = fmaf(wv, oh[16 + 3 * i + 0], vacc[jj][0]);
                vacc[jj][1] = fmaf(wv, oh[16 + 3 * i + 1], vacc[jj][1]);
                vacc[jj][2] = fmaf(wv, oh[16 + 3 * i + 2], vacc[jj][2]);
            }
        }
        __syncthreads();   // T reused next h
    }

    #pragma unroll
    for (int jj = 0; jj < 16; jj++)
        out[(size_t)n * 64 + w * 16 + jj] = aacc[jj];
    float* outv = out + (size_t)Nq * 64;
    #pragma unroll
    for (int jj = 0; jj < 4; jj++)
        #pragma unroll
        for (int v = 0; v < 3; v++)
            outv[((size_t)n * 16 + w * 4 + jj) * 3 + v] = vacc[jj][v];
}

// ---------------------------------------------------------------------------
extern "C" void kernel_launch(void* const* d_in, const int* in_sizes, int n_in,
                              void* d_out, int out_size, void* d_ws, size_t ws_size,
                              hipStream_t stream)
{
    const float* ax    = (const float*)d_in[0];
    const float* vx    = (const float*)d_in[1];
    const float* pos_k = (const float*)d_in[2];
    const float* pos_q = (const float*)d_in[3];
    const float* Waq   = (const float*)d_in[4];
    const float* Wvq   = (const float*)d_in[5];
    const float* Wak   = (const float*)d_in[6];
    const float* Wvk   = (const float*)d_in[7];
    const float* Wav   = (const float*)d_in[8];
    const float* Wvv   = (const float*)d_in[9];
    const float* Wao   = (const float*)d_in[10];
    const float* Wvo   = (const float*)d_in[11];
    float* out = (float*)d_out;

    const size_t MB = 1024 * 1024;
    char* ws = (char*)d_ws;
    // layout: Q(2MB) K(2MB) Vt(2MB) pq4(256K) pk4(256K) partO(16.8MB) partL(256K)
    ushortT* Qg   = (ushortT*)(ws);
    ushortT* Kg   = (ushortT*)(ws + 2*MB);
    ushortT* Vtg  = (ushortT*)(ws + 4*MB);
    floatx4* pq4  = (floatx4*)(ws + 6*MB);
    floatx4* pk4  = (floatx4*)(ws + 6*MB + (size_t)H*Nq*16);
    float*  partO = (float*)(ws + 6*MB + (size_t)2*H*Nq*16);
    float*  partL = (float*)((char*)partO + (size_t)H*SEG*Nq*64*4);

    pos_prep_kernel<<<dim3(Nq/256, H), 256, 0, stream>>>(pos_q, pos_k, pq4, pk4);
    qkv_kernel<<<dim3(Nq/256, H, 6), 256, 0, stream>>>(
        ax, vx, Waq, Wvq, Wak, Wvk, Wav, Wvv, Qg, Kg, Vtg);
    attn_kernel<<<dim3(Nq/64, H, SEG), 128, 0, stream>>>(
        Qg, Kg, Vtg, pq4, pk4, partO, partL);
    finish_kernel<<<dim3(Nq/64), 256, 0, stream>>>(partO, partL, Wao, Wvo, out);
}